// Round 4
// baseline (635.566 us; speedup 1.0000x reference)
//
#include <hip/hip_runtime.h>
#include <stdint.h>

#define D_MODEL 1024
#define SEQ 2048
#define HALF 1024
#define K_EIG 24
#define WE_ROWS 1120   // 1024 + 96 zero pad (prefetch overrun)
#define GUARD 80       // zero rows before EACH slice
#define HALF_P (HALF + GUARD)   // padded slice stride (rows)

typedef __attribute__((ext_vector_type(8))) short bf16x8;
typedef __attribute__((ext_vector_type(4))) float f32x4;

#define GAS __attribute__((address_space(1)))
#define LAS __attribute__((address_space(3)))

static __device__ __forceinline__ unsigned short f2bf(float f) {
  union { float f; uint32_t u; } v; v.f = f;
  uint32_t u = v.u;
  u += 0x7FFFu + ((u >> 16) & 1u);
  return (unsigned short)(u >> 16);
}

// ---------------- x (fp32) -> bf16 ----------------
__global__ void k_convert_x(const float* __restrict__ x, unsigned short* __restrict__ xb, int n4) {
  int idx = blockIdx.x * blockDim.x + threadIdx.x;
  if (idx < n4) {
    float4 v = ((const float4*)x)[idx];
    ushort4 o;
    o.x = f2bf(v.x); o.y = f2bf(v.y); o.z = f2bf(v.z); o.w = f2bf(v.w);
    ((ushort4*)xb)[idx] = o;
  }
}

// ---------------- zero the per-slice guard rows of u ----------------
__global__ void k_zero_guard(float* __restrict__ u) {
  // 8 slices x GUARD rows x 1024 f32 = 163840 float4
  int idx = blockIdx.x * blockDim.x + threadIdx.x;
  int r = idx / (GUARD * 256);          // GUARD*1024/4 float4 per slice guard
  int off = idx - r * (GUARD * 256);
  ((float4*)u)[(size_t)r * (HALF_P * 256) + off] = make_float4(0.f, 0.f, 0.f, 0.f);
}

// ------------- M_inputs [K][N] fp32 -> Mt [N][K] bf16 -------------
__global__ void k_transpose_M(const float* __restrict__ M, unsigned short* __restrict__ Mt) {
  __shared__ float tile[32][33];
  int k0 = blockIdx.y * 32, n0 = blockIdx.x * 32;
  int tx = threadIdx.x & 31, ty = threadIdx.x >> 5;
  #pragma unroll
  for (int r = 0; r < 32; r += 8)
    tile[ty + r][tx] = M[(size_t)(k0 + ty + r) * D_MODEL + n0 + tx];
  __syncthreads();
  #pragma unroll
  for (int r = 0; r < 32; r += 8)
    Mt[(size_t)(n0 + ty + r) * D_MODEL + k0 + tx] = f2bf(tile[tx][ty + r]);
}

// ------------- w_e[j][d] = 2 * sum_k phi[2j][k] * Mf[k][d]; rows >= HALF are zero -------------
__global__ void k_we(const float* __restrict__ phi, const float* __restrict__ Mf,
                     float* __restrict__ we) {
  int j = blockIdx.x;                  // 0..WE_ROWS-1
  if (j >= HALF) {
    for (int d = threadIdx.x; d < D_MODEL; d += blockDim.x)
      we[(size_t)j * D_MODEL + d] = 0.f;
    return;
  }
  __shared__ float ph[K_EIG];
  if (threadIdx.x < K_EIG) ph[threadIdx.x] = phi[(size_t)(2 * j) * K_EIG + threadIdx.x];
  __syncthreads();
  for (int d = threadIdx.x; d < D_MODEL; d += blockDim.x) {
    float s = 0.f;
    #pragma unroll
    for (int k = 0; k < K_EIG; ++k) s = fmaf(ph[k], Mf[(size_t)k * D_MODEL + d], s);
    we[(size_t)j * D_MODEL + d] = 2.0f * s;
  }
}

// ------------- u = x @ M  (bf16 MFMA, B^T input), epilogue remaps to padded u_h[r][GUARD+i][d] -------------
__global__ __launch_bounds__(256) void k_gemm(const unsigned short* __restrict__ A,
                                              const unsigned short* __restrict__ Bt,
                                              float* __restrict__ U) {
  __shared__ unsigned short As[128 * 32];
  __shared__ unsigned short Bs[128 * 32];
  const int m0 = (int)blockIdx.x * 128;
  const int n0 = (int)blockIdx.y * 128;
  const int tid = threadIdx.x;
  const int lane = tid & 63;
  const int wave = tid >> 6;
  const int wm = wave >> 1, wn = wave & 1;
  const int srow = lane >> 2;
  const int skoff = (lane & 3) * 8;

  f32x4 acc[4][4] = {};

  for (int k0 = 0; k0 < 1024; k0 += 32) {
    __syncthreads();
    #pragma unroll
    for (int c = 0; c < 2; ++c) {
      int rbase = wave * 32 + c * 16;
      const unsigned short* src = A + (size_t)(m0 + rbase + srow) * 1024 + k0 + skoff;
      __builtin_amdgcn_global_load_lds((const GAS void*)src, (LAS void*)(As + rbase * 32), 16, 0, 0);
    }
    #pragma unroll
    for (int c = 0; c < 2; ++c) {
      int rbase = wave * 32 + c * 16;
      const unsigned short* src = Bt + (size_t)(n0 + rbase + srow) * 1024 + k0 + skoff;
      __builtin_amdgcn_global_load_lds((const GAS void*)src, (LAS void*)(Bs + rbase * 32), 16, 0, 0);
    }
    __syncthreads();

    bf16x8 a[4], b[4];
    #pragma unroll
    for (int mt = 0; mt < 4; ++mt)
      a[mt] = *(const bf16x8*)(As + ((wm * 64 + mt * 16 + (lane & 15)) * 32 + (lane >> 4) * 8));
    #pragma unroll
    for (int nt = 0; nt < 4; ++nt)
      b[nt] = *(const bf16x8*)(Bs + ((wn * 64 + nt * 16 + (lane & 15)) * 32 + (lane >> 4) * 8));
    #pragma unroll
    for (int mt = 0; mt < 4; ++mt)
      #pragma unroll
      for (int nt = 0; nt < 4; ++nt)
        acc[mt][nt] = __builtin_amdgcn_mfma_f32_16x16x32_bf16(a[mt], b[nt], acc[mt][nt], 0, 0, 0);
  }

  const int crow = (lane >> 4) * 4;
  const int ccol = lane & 15;
  #pragma unroll
  for (int mt = 0; mt < 4; ++mt) {
    #pragma unroll
    for (int q = 0; q < 4; ++q) {
      int m = m0 + wm * 64 + mt * 16 + crow + q;
      int b_ = m >> 11;
      int t = m & 2047;
      int r = (b_ << 1) | (t & 1);
      int i = t >> 1;
      float* dst = U + ((size_t)r * HALF_P + GUARD + i) * D_MODEL;
      #pragma unroll
      for (int nt = 0; nt < 4; ++nt)
        dst[n0 + wn * 64 + nt * 16 + ccol] = acc[mt][nt][q];
    }
  }
}

// ------------- depthwise causal conv: register sliding window, 16 outputs/thread -------------
__device__ __forceinline__ void pref_u(const float* __restrict__ ub, int urow, float (&buf)[8]) {
#pragma unroll
  for (int t = 0; t < 8; ++t)
    buf[t] = *(ub + (long long)(urow - t) * D_MODEL);   // per-slice guard rows make this safe
}

__device__ __forceinline__ void pref_w(const float* __restrict__ wb, int wrow, float (&buf)[8]) {
#pragma unroll
  for (int t = 0; t < 8; ++t)
    buf[t] = *(wb + (long long)(wrow + t) * D_MODEL);   // zero-padded rows
}

template <int PH>   // PH = starting tap phase & 15 (0 or 8)
__device__ __forceinline__ void tap_group(const float (&cu)[8], const float (&cw)[8],
                                          float (&win)[16], float (&acc)[16]) {
#pragma unroll
  for (int t = 0; t < 8; ++t) {
    const int kf = (PH + t) & 15;
    float wv = cw[t];
#pragma unroll
    for (int o = 0; o < 16; ++o)
      acc[o] = fmaf(wv, win[(o - kf) & 15], acc[o]);
    win[(15 - kf) & 15] = cu[t];
  }
}

__global__ __launch_bounds__(256, 4) void k_conv(const float* __restrict__ u,
                                                 const float* __restrict__ we,
                                                 float* __restrict__ out) {
  // XCD-locality swizzle: all blocks of a d-pair land on one XCD (round-robin model)
  const int flat = blockIdx.x;                     // 0..1023
  const int d_t = ((flat & 7) << 1) | ((flat >> 3) & 1);   // 0..15
  const int pp  = (flat >> 4) & 7;                 // 0..7 tile pair
  const int r   = flat >> 7;                       // 0..7
  const int d0 = d_t * 64;
  const int tid = threadIdx.x;
  const int dl = tid & 63;
  const int ig = tid >> 6;

  const float* ub = u + ((size_t)r * HALF_P + GUARD) * D_MODEL + d0 + dl;
  const float* wb = we + d0 + dl;
  const int b_ = r >> 1, p = r & 1;

#pragma unroll 1
  for (int tt = 0; tt < 2; ++tt) {
    const int a = tt ? pp : (15 - pp);   // heavy tile first; every block: 17 chunks total
    const int i0 = a * 64;
    const int ibase = i0 + ig * 16;

    float acc[16], win[16];
#pragma unroll
    for (int o = 0; o < 16; ++o) {
      acc[o] = 0.f;
      win[o] = *(ub + (long long)(ibase + o) * D_MODEL);
    }

    float bu0[8], bu1[8], bw0[8], bw1[8];
    int urow = ibase - 1, wrow = 0;
    pref_u(ub, urow, bu0); urow -= 8;
    pref_w(wb, wrow, bw0); wrow += 8;

    const int niter = a + 1;   // 64-tap chunks
#pragma unroll 1
    for (int it = 0; it < niter; ++it) {
      pref_u(ub, urow, bu1); urow -= 8; pref_w(wb, wrow, bw1); wrow += 8;
      tap_group<0>(bu0, bw0, win, acc);
      pref_u(ub, urow, bu0); urow -= 8; pref_w(wb, wrow, bw0); wrow += 8;
      tap_group<8>(bu1, bw1, win, acc);
      pref_u(ub, urow, bu1); urow -= 8; pref_w(wb, wrow, bw1); wrow += 8;
      tap_group<0>(bu0, bw0, win, acc);
      pref_u(ub, urow, bu0); urow -= 8; pref_w(wb, wrow, bw0); wrow += 8;
      tap_group<8>(bu1, bw1, win, acc);
      pref_u(ub, urow, bu1); urow -= 8; pref_w(wb, wrow, bw1); wrow += 8;
      tap_group<0>(bu0, bw0, win, acc);
      pref_u(ub, urow, bu0); urow -= 8; pref_w(wb, wrow, bw0); wrow += 8;
      tap_group<8>(bu1, bw1, win, acc);
      pref_u(ub, urow, bu1); urow -= 8; pref_w(wb, wrow, bw1); wrow += 8;
      tap_group<0>(bu0, bw0, win, acc);
      pref_u(ub, urow, bu0); urow -= 8; pref_w(wb, wrow, bw0); wrow += 8;
      tap_group<8>(bu1, bw1, win, acc);
    }

#pragma unroll
    for (int o = 0; o < 16; ++o)
      out[((size_t)b_ * SEQ + 2 * (ibase + o) + p) * D_MODEL + d0 + dl] = acc[o];
  }
}

extern "C" void kernel_launch(void* const* d_in, const int* in_sizes, int n_in,
                              void* d_out, int out_size, void* d_ws, size_t ws_size,
                              hipStream_t stream) {
  const float* x   = (const float*)d_in[0];   // [4][2048][1024]
  const float* Mi  = (const float*)d_in[1];   // [1024][1024]
  const float* Mf  = (const float*)d_in[2];   // [24][1024]
  const float* phi = (const float*)d_in[3];   // [2048][24]
  float* out = (float*)d_out;

  // x_bf scratch lives in d_out (32MB) -- dead before conv writes out.
  unsigned short* x_bf = (unsigned short*)d_out;               // 16 MB

  char* ws = (char*)d_ws;
  unsigned short* Mt = (unsigned short*)(ws);                  // 2 MB
  float* we          = (float*)(ws + (2u << 20));              // 4.375 MB
  float* u           = (float*)(ws + (7u << 20));              // 8*1104*1024*4 = 34.5 MB

  hipLaunchKernelGGL(k_zero_guard, dim3(640), dim3(256), 0, stream, u);
  hipLaunchKernelGGL(k_convert_x, dim3(8192), dim3(256), 0, stream, x, x_bf, 2097152);
  hipLaunchKernelGGL(k_transpose_M, dim3(32, 32), dim3(256), 0, stream, Mi, Mt);
  hipLaunchKernelGGL(k_we, dim3(WE_ROWS), dim3(256), 0, stream, phi, Mf, we);
  hipLaunchKernelGGL(k_gemm, dim3(64, 8), dim3(256), 0, stream, x_bf, Mt, u);
  hipLaunchKernelGGL(k_conv, dim3(1024), dim3(256), 0, stream, u, we, out);
}

// Round 5
// 234.719 us; speedup vs baseline: 2.7078x; 2.7078x over previous
//
#include <hip/hip_runtime.h>
#include <stdint.h>

#define D_MODEL 1024
#define SEQ 2048
#define HALF 1024
#define K_EIG 24
#define WE_ROWS 1120   // 1024 + 96 zero pad (w prefetch overrun)
#define GUARD 192      // zero rows before EACH slice (lowest staged row = -192)
#define HALF_P (HALF + GUARD)   // padded slice stride (rows)

typedef __attribute__((ext_vector_type(8))) short bf16x8;
typedef __attribute__((ext_vector_type(4))) float f32x4;

#define GAS __attribute__((address_space(1)))
#define LAS __attribute__((address_space(3)))

static __device__ __forceinline__ unsigned short f2bf(float f) {
  union { float f; uint32_t u; } v; v.f = f;
  uint32_t u = v.u;
  u += 0x7FFFu + ((u >> 16) & 1u);
  return (unsigned short)(u >> 16);
}

// ---------------- x (fp32) -> bf16 ----------------
__global__ void k_convert_x(const float* __restrict__ x, unsigned short* __restrict__ xb, int n4) {
  int idx = blockIdx.x * blockDim.x + threadIdx.x;
  if (idx < n4) {
    float4 v = ((const float4*)x)[idx];
    ushort4 o;
    o.x = f2bf(v.x); o.y = f2bf(v.y); o.z = f2bf(v.z); o.w = f2bf(v.w);
    ((ushort4*)xb)[idx] = o;
  }
}

// ---------------- zero the per-slice guard rows of u ----------------
__global__ void k_zero_guard(float* __restrict__ u) {
  // 8 slices x GUARD rows x 1024 f32 = 393216 float4
  int idx = blockIdx.x * blockDim.x + threadIdx.x;
  int r = idx / (GUARD * 256);
  int off = idx - r * (GUARD * 256);
  ((float4*)u)[(size_t)r * (HALF_P * 256) + off] = make_float4(0.f, 0.f, 0.f, 0.f);
}

// ------------- M_inputs [K][N] fp32 -> Mt [N][K] bf16 -------------
__global__ void k_transpose_M(const float* __restrict__ M, unsigned short* __restrict__ Mt) {
  __shared__ float tile[32][33];
  int k0 = blockIdx.y * 32, n0 = blockIdx.x * 32;
  int tx = threadIdx.x & 31, ty = threadIdx.x >> 5;
  #pragma unroll
  for (int r = 0; r < 32; r += 8)
    tile[ty + r][tx] = M[(size_t)(k0 + ty + r) * D_MODEL + n0 + tx];
  __syncthreads();
  #pragma unroll
  for (int r = 0; r < 32; r += 8)
    Mt[(size_t)(n0 + ty + r) * D_MODEL + k0 + tx] = f2bf(tile[tx][ty + r]);
}

// ------------- w_e[j][d] = 2 * sum_k phi[2j][k] * Mf[k][d]; rows >= HALF are zero -------------
__global__ void k_we(const float* __restrict__ phi, const float* __restrict__ Mf,
                     float* __restrict__ we) {
  int j = blockIdx.x;
  if (j >= HALF) {
    for (int d = threadIdx.x; d < D_MODEL; d += blockDim.x)
      we[(size_t)j * D_MODEL + d] = 0.f;
    return;
  }
  __shared__ float ph[K_EIG];
  if (threadIdx.x < K_EIG) ph[threadIdx.x] = phi[(size_t)(2 * j) * K_EIG + threadIdx.x];
  __syncthreads();
  for (int d = threadIdx.x; d < D_MODEL; d += blockDim.x) {
    float s = 0.f;
    #pragma unroll
    for (int k = 0; k < K_EIG; ++k) s = fmaf(ph[k], Mf[(size_t)k * D_MODEL + d], s);
    we[(size_t)j * D_MODEL + d] = 2.0f * s;
  }
}

// ------------- u = x @ M (bf16 MFMA, B^T input), epilogue writes padded u_h[r][GUARD+i][d] -------------
__global__ __launch_bounds__(256) void k_gemm(const unsigned short* __restrict__ A,
                                              const unsigned short* __restrict__ Bt,
                                              float* __restrict__ U) {
  __shared__ unsigned short As[128 * 32];
  __shared__ unsigned short Bs[128 * 32];
  const int m0 = (int)blockIdx.x * 128;
  const int n0 = (int)blockIdx.y * 128;
  const int tid = threadIdx.x;
  const int lane = tid & 63;
  const int wave = tid >> 6;
  const int wm = wave >> 1, wn = wave & 1;
  const int srow = lane >> 2;
  const int skoff = (lane & 3) * 8;

  f32x4 acc[4][4] = {};

  for (int k0 = 0; k0 < 1024; k0 += 32) {
    __syncthreads();
    #pragma unroll
    for (int c = 0; c < 2; ++c) {
      int rbase = wave * 32 + c * 16;
      const unsigned short* src = A + (size_t)(m0 + rbase + srow) * 1024 + k0 + skoff;
      __builtin_amdgcn_global_load_lds((const GAS void*)src, (LAS void*)(As + rbase * 32), 16, 0, 0);
    }
    #pragma unroll
    for (int c = 0; c < 2; ++c) {
      int rbase = wave * 32 + c * 16;
      const unsigned short* src = Bt + (size_t)(n0 + rbase + srow) * 1024 + k0 + skoff;
      __builtin_amdgcn_global_load_lds((const GAS void*)src, (LAS void*)(Bs + rbase * 32), 16, 0, 0);
    }
    __syncthreads();

    bf16x8 a[4], b[4];
    #pragma unroll
    for (int mt = 0; mt < 4; ++mt)
      a[mt] = *(const bf16x8*)(As + ((wm * 64 + mt * 16 + (lane & 15)) * 32 + (lane >> 4) * 8));
    #pragma unroll
    for (int nt = 0; nt < 4; ++nt)
      b[nt] = *(const bf16x8*)(Bs + ((wn * 64 + nt * 16 + (lane & 15)) * 32 + (lane >> 4) * 8));
    #pragma unroll
    for (int mt = 0; mt < 4; ++mt)
      #pragma unroll
      for (int nt = 0; nt < 4; ++nt)
        acc[mt][nt] = __builtin_amdgcn_mfma_f32_16x16x32_bf16(a[mt], b[nt], acc[mt][nt], 0, 0, 0);
  }

  const int crow = (lane >> 4) * 4;
  const int ccol = lane & 15;
  #pragma unroll
  for (int mt = 0; mt < 4; ++mt) {
    #pragma unroll
    for (int q = 0; q < 4; ++q) {
      int m = m0 + wm * 64 + mt * 16 + crow + q;
      int b_ = m >> 11;
      int t = m & 2047;
      int r = (b_ << 1) | (t & 1);
      int i = t >> 1;
      float* dst = U + ((size_t)r * HALF_P + GUARD + i) * D_MODEL;
      #pragma unroll
      for (int nt = 0; nt < 4; ++nt)
        dst[n0 + wn * 64 + nt * 16 + ccol] = acc[mt][nt][q];
    }
  }
}

// ------------- depthwise causal conv: rolling circular LDS u-buffer + register window -------------
// 512 thr = 64 d-lanes x 8 waves (wave = 16 outputs/thread). i-tile 128, pairs (a,7-a): 18 chunks/block.
template <int PH>
__device__ __forceinline__ void tap_group(const float (&cu)[8], const float (&cw)[8],
                                          float (&win)[16], float (&acc)[16]) {
#pragma unroll
  for (int t = 0; t < 8; ++t) {
    const int kf = (PH + t) & 15;
    float wv = cw[t];
#pragma unroll
    for (int o = 0; o < 16; ++o)
      acc[o] = fmaf(wv, win[(o - kf) & 15], acc[o]);
    win[(15 - kf) & 15] = cu[t];
  }
}

__global__ __launch_bounds__(512, 4) void k_conv(const float* __restrict__ u,
                                                 const float* __restrict__ we,
                                                 float* __restrict__ out) {
  __shared__ float u_s[256 * 64];   // 64KB circular row buffer (slot = row & 255)
  const int flat = blockIdx.x;                 // 0..511
  const int dt = flat & 15;                    // flat&7 = dt&7 -> d-column pinned to one XCD
  const int r  = (flat >> 4) & 7;
  const int pp = flat >> 7;                    // 0..3
  const int d0 = dt * 64;
  const int tid = threadIdx.x;
  const int dl = tid & 63;                     // lane
  const int ig = tid >> 6;                     // wave 0..7

  const float* ubase = u + ((size_t)r * HALF_P + GUARD) * D_MODEL;   // row-relative (+row*1024)
  const float* wb = we + d0 + dl;
  const int b_ = r >> 1, p = r & 1;

  // stage GPW groups of 4 rows per wave, rows lo.. (lo 64-aligned)
#define STAGE(lo, GPW)                                                                  \
  {                                                                                     \
    _Pragma("unroll") for (int q = 0; q < (GPW); ++q) {                                 \
      int row = (lo) + 4 * (ig * (GPW) + q);                                            \
      const float* src = ubase + (size_t)(row + (dl >> 4)) * D_MODEL + d0 + (dl & 15) * 4; \
      __builtin_amdgcn_global_load_lds((const GAS void*)src,                            \
                                       (LAS void*)(u_s + (row & 255) * 64), 16, 0, 0);  \
    }                                                                                   \
  }

#define LDSU(buf)                                                                       \
  {                                                                                     \
    _Pragma("unroll") for (int t = 0; t < 8; ++t)                                       \
      buf[t] = u_s[((urow - t) & 255) * 64 + dl];                                       \
    urow -= 8;                                                                          \
  }

#define PW(buf)                                                                         \
  {                                                                                     \
    _Pragma("unroll") for (int t = 0; t < 8; ++t)                                       \
      buf[t] = wb[(size_t)(wrow + t) * D_MODEL];                                        \
    wrow += 8;                                                                          \
  }

#pragma unroll 1
  for (int tt = 0; tt < 2; ++tt) {
    const int a = tt ? pp : (7 - pp);   // heavy tile first; 18 chunks total per block
    const int i0 = a * 128;
    const int ibase = i0 + ig * 16;
    const int niter = 2 * a + 2;        // 64-tap chunks

    STAGE(i0 - 64, 6);                  // rows [i0-64, i0+128)
    __syncthreads();

    float acc[16], win[16];
#pragma unroll
    for (int o = 0; o < 16; ++o) {
      acc[o] = 0.f;
      win[o] = u_s[((ibase + o) & 255) * 64 + dl];
    }

    float bu0[8], bu1[8], bw0[8], bw1[8];
    int urow = ibase - 1, wrow = 0;
    PW(bw0);

#pragma unroll 1
    for (int c = 0; c < niter; ++c) {
      STAGE(i0 - 64 * c - 128, 2);      // stage rows for chunk c+1, overlapped with compute
      LDSU(bu0);                        // group 0 refills (rows staged in prior chunks)
      PW(bw1); LDSU(bu1); tap_group<0>(bu0, bw0, win, acc);
      PW(bw0); LDSU(bu0); tap_group<8>(bu1, bw1, win, acc);
      PW(bw1); LDSU(bu1); tap_group<0>(bu0, bw0, win, acc);
      PW(bw0); LDSU(bu0); tap_group<8>(bu1, bw1, win, acc);
      PW(bw1); LDSU(bu1); tap_group<0>(bu0, bw0, win, acc);
      PW(bw0); LDSU(bu0); tap_group<8>(bu1, bw1, win, acc);
      PW(bw1); LDSU(bu1); tap_group<0>(bu0, bw0, win, acc);
      PW(bw0);            tap_group<8>(bu1, bw1, win, acc);   // no LDS lookahead across barrier
      __syncthreads();
    }

#pragma unroll
    for (int o = 0; o < 16; ++o)
      out[((size_t)b_ * SEQ + 2 * (ibase + o) + p) * D_MODEL + d0 + dl] = acc[o];
  }
#undef STAGE
#undef LDSU
#undef PW
}

extern "C" void kernel_launch(void* const* d_in, const int* in_sizes, int n_in,
                              void* d_out, int out_size, void* d_ws, size_t ws_size,
                              hipStream_t stream) {
  const float* x   = (const float*)d_in[0];   // [4][2048][1024]
  const float* Mi  = (const float*)d_in[1];   // [1024][1024]
  const float* Mf  = (const float*)d_in[2];   // [24][1024]
  const float* phi = (const float*)d_in[3];   // [2048][24]
  float* out = (float*)d_out;

  // x_bf (16MB) and Mt (2MB) live in d_out -- dead before conv writes out.
  unsigned short* x_bf = (unsigned short*)d_out;
  unsigned short* Mt   = (unsigned short*)((char*)d_out + (16u << 20));

  char* ws = (char*)d_ws;
  float* we = (float*)(ws);                    // 4.59 MB
  float* u  = (float*)(ws + (5u << 20));       // 8*1216*1024*4 = 39.85 MB

  hipLaunchKernelGGL(k_zero_guard, dim3(1536), dim3(256), 0, stream, u);
  hipLaunchKernelGGL(k_convert_x, dim3(8192), dim3(256), 0, stream, x, x_bf, 2097152);
  hipLaunchKernelGGL(k_transpose_M, dim3(32, 32), dim3(256), 0, stream, Mi, Mt);
  hipLaunchKernelGGL(k_we, dim3(WE_ROWS), dim3(256), 0, stream, phi, Mf, we);
  hipLaunchKernelGGL(k_gemm, dim3(64, 8), dim3(256), 0, stream, x_bf, Mt, u);
  hipLaunchKernelGGL(k_conv, dim3(512), dim3(512), 0, stream, u, we, out);
}